// Round 6
// baseline (348.526 us; speedup 1.0000x reference)
//
#include <hip/hip_runtime.h>
#include <math.h>

// LabelSmoothing KL-div loss, closed form, two-pass.
// Inputs: d_in[0] = predicted log-probs, fp32, (16,128,32000) flat.
//         d_in[1] = targets, int, (2048,).
// Output: d_out[0] = scalar fp32 sum.
//
// Per non-pad row: C - eps*(rowsum - p[0] - p[t]) - 0.9*p[t]
//   eps = 0.1/(V-2), C = (V-2)*eps*ln(eps) + 0.9*ln(0.9)
//
// Pass 1: one block per row; row = 8000 float4, 7 unrolled iters of 4
//         independent streams + fixed tail. PLAIN cached loads (R6 A/B vs
//         R5's nontemporal): the harness's d_in restore just wrote all
//         262 MB of pred, so most of it should be Infinity-Cache-resident;
//         nt's no-allocate hint may read around the LLC and forfeit that.
// Pass 2: one block sums the 2048 partials -> d_out[0] (overwrites poison).

#define V 32000
#define NROWS 2048
#define BLOCK 256

typedef float vf4 __attribute__((ext_vector_type(4)));

__global__ __launch_bounds__(BLOCK) void
ls_row_kernel(const float* __restrict__ pred,
              const int* __restrict__ tgt,
              float* __restrict__ partials,
              float C, float eps) {
    const int row = blockIdx.x;
    const int t = threadIdx.x;
    const float* __restrict__ p = pred + (size_t)row * V;
    const vf4* __restrict__ p4 = (const vf4*)p;

    // Prefetch epilogue operands early (thread 0 only); resolved long before use.
    int pre_t = 0;
    float pre_p0 = 0.f, pre_pt = 0.f;
    if (t == 0) {
        pre_t = tgt[row];
        pre_p0 = p[0];
        pre_pt = p[pre_t];
    }

    // 4 independent accumulator streams.
    vf4 s0 = {0.f, 0.f, 0.f, 0.f};
    vf4 s1 = {0.f, 0.f, 0.f, 0.f};
    vf4 s2 = {0.f, 0.f, 0.f, 0.f};
    vf4 s3 = {0.f, 0.f, 0.f, 0.f};

    #pragma unroll
    for (int j = 0; j < 7; ++j) {
        const int base = j * 1024 + t;
        vf4 a = p4[base];
        vf4 b = p4[base + 256];
        vf4 c = p4[base + 512];
        vf4 d = p4[base + 768];
        s0 += a;
        s1 += b;
        s2 += c;
        s3 += d;
    }
    // Tail: 7168..7999 = 3*256 + 64 float4s.
    {
        vf4 a = p4[7168 + t];
        vf4 b = p4[7424 + t];
        vf4 c = p4[7680 + t];
        s0 += a;
        s1 += b;
        s2 += c;
        if (t < 64) {
            vf4 d = p4[7936 + t];
            s3 += d;
        }
    }

    vf4 s = (s0 + s1) + (s2 + s3);
    float partial = (s.x + s.y) + (s.z + s.w);

    // wave-64 reduce
    #pragma unroll
    for (int off = 32; off > 0; off >>= 1)
        partial += __shfl_down(partial, off, 64);

    __shared__ float smem[BLOCK / 64];
    const int lane = threadIdx.x & 63;
    const int wave = threadIdx.x >> 6;
    if (lane == 0) smem[wave] = partial;
    __syncthreads();

    if (t == 0) {
        float rowsum = smem[0] + smem[1] + smem[2] + smem[3];
        float contrib = 0.0f;
        if (pre_t != 0) {  // PAD_IDX row -> contributes 0
            contrib = C - eps * (rowsum - pre_p0 - pre_pt) - 0.9f * pre_pt;
        }
        partials[row] = contrib;  // plain store, no init required
    }
}

__global__ __launch_bounds__(BLOCK) void
ls_final_kernel(const float* __restrict__ partials, float* __restrict__ out) {
    float s = 0.0f;
    for (int i = threadIdx.x; i < NROWS; i += BLOCK)
        s += partials[i];

    #pragma unroll
    for (int off = 32; off > 0; off >>= 1)
        s += __shfl_down(s, off, 64);

    __shared__ float smem[BLOCK / 64];
    const int lane = threadIdx.x & 63;
    const int wave = threadIdx.x >> 6;
    if (lane == 0) smem[wave] = s;
    __syncthreads();

    if (threadIdx.x == 0)
        out[0] = smem[0] + smem[1] + smem[2] + smem[3];
}

extern "C" void kernel_launch(void* const* d_in, const int* in_sizes, int n_in,
                              void* d_out, int out_size, void* d_ws, size_t ws_size,
                              hipStream_t stream) {
    const float* pred = (const float*)d_in[0];
    const int* tgt = (const int*)d_in[1];
    float* out = (float*)d_out;
    float* partials = (float*)d_ws;  // NROWS floats, all written by pass 1

    const double eps_d = 0.1 / (double)(V - 2);
    const double C_d = (double)(V - 2) * eps_d * log(eps_d) + 0.9 * log(0.9);

    ls_row_kernel<<<NROWS, BLOCK, 0, stream>>>(pred, tgt, partials,
                                               (float)C_d, (float)eps_d);
    ls_final_kernel<<<1, BLOCK, 0, stream>>>(partials, out);
}

// Round 7
// 324.760 us; speedup vs baseline: 1.0732x; 1.0732x over previous
//
#include <hip/hip_runtime.h>
#include <math.h>

// LabelSmoothing KL-div loss, closed form, two-pass.
// Inputs: d_in[0] = predicted log-probs, fp32, (16,128,32000) flat.
//         d_in[1] = targets, int, (2048,).
// Output: d_out[0] = scalar fp32 sum.
//
// Per non-pad row: C - eps*(rowsum - p[0] - p[t]) - 0.9*p[t]
//   eps = 0.1/(V-2), C = (V-2)*eps*ln(eps) + 0.9*ln(0.9)
//
// Pass 1: one block per row; row = 8000 float4, 7 unrolled iters of 4
//         independent streams + fixed tail; NONTEMPORAL loads.
//         R6 A/B measured: NT = 326.8 us, plain cached = 348.5 us.
//         The 1 GB ws-poison fill precedes us in the graph -> L2 is full of
//         dirty lines; cached reads allocate + force eviction interleave,
//         NT reads bypass allocation. Keep NT.
// Pass 2: one block sums the 2048 partials -> d_out[0] (overwrites poison).

#define V 32000
#define NROWS 2048
#define BLOCK 256

// Native Clang vector type: __builtin_nontemporal_load rejects
// HIP_vector_type<float,4>* but accepts vectors of scalars.
typedef float vf4 __attribute__((ext_vector_type(4)));

__global__ __launch_bounds__(BLOCK) void
ls_row_kernel(const float* __restrict__ pred,
              const int* __restrict__ tgt,
              float* __restrict__ partials,
              float C, float eps) {
    const int row = blockIdx.x;
    const int t = threadIdx.x;
    const float* __restrict__ p = pred + (size_t)row * V;
    const vf4* __restrict__ p4 = (const vf4*)p;

    // Prefetch epilogue operands early (thread 0 only); resolved long before use.
    int pre_t = 0;
    float pre_p0 = 0.f, pre_pt = 0.f;
    if (t == 0) {
        pre_t = tgt[row];
        pre_p0 = p[0];
        pre_pt = p[pre_t];
    }

    // 4 independent accumulator streams.
    vf4 s0 = {0.f, 0.f, 0.f, 0.f};
    vf4 s1 = {0.f, 0.f, 0.f, 0.f};
    vf4 s2 = {0.f, 0.f, 0.f, 0.f};
    vf4 s3 = {0.f, 0.f, 0.f, 0.f};

    #pragma unroll
    for (int j = 0; j < 7; ++j) {
        const int base = j * 1024 + t;
        vf4 a = __builtin_nontemporal_load(&p4[base]);
        vf4 b = __builtin_nontemporal_load(&p4[base + 256]);
        vf4 c = __builtin_nontemporal_load(&p4[base + 512]);
        vf4 d = __builtin_nontemporal_load(&p4[base + 768]);
        s0 += a;
        s1 += b;
        s2 += c;
        s3 += d;
    }
    // Tail: 7168..7999 = 3*256 + 64 float4s.
    {
        vf4 a = __builtin_nontemporal_load(&p4[7168 + t]);
        vf4 b = __builtin_nontemporal_load(&p4[7424 + t]);
        vf4 c = __builtin_nontemporal_load(&p4[7680 + t]);
        s0 += a;
        s1 += b;
        s2 += c;
        if (t < 64) {
            vf4 d = __builtin_nontemporal_load(&p4[7936 + t]);
            s3 += d;
        }
    }

    vf4 s = (s0 + s1) + (s2 + s3);
    float partial = (s.x + s.y) + (s.z + s.w);

    // wave-64 reduce
    #pragma unroll
    for (int off = 32; off > 0; off >>= 1)
        partial += __shfl_down(partial, off, 64);

    __shared__ float smem[BLOCK / 64];
    const int lane = threadIdx.x & 63;
    const int wave = threadIdx.x >> 6;
    if (lane == 0) smem[wave] = partial;
    __syncthreads();

    if (t == 0) {
        float rowsum = smem[0] + smem[1] + smem[2] + smem[3];
        float contrib = 0.0f;
        if (pre_t != 0) {  // PAD_IDX row -> contributes 0
            contrib = C - eps * (rowsum - pre_p0 - pre_pt) - 0.9f * pre_pt;
        }
        partials[row] = contrib;  // plain store, no init required
    }
}

__global__ __launch_bounds__(BLOCK) void
ls_final_kernel(const float* __restrict__ partials, float* __restrict__ out) {
    float s = 0.0f;
    for (int i = threadIdx.x; i < NROWS; i += BLOCK)
        s += partials[i];

    #pragma unroll
    for (int off = 32; off > 0; off >>= 1)
        s += __shfl_down(s, off, 64);

    __shared__ float smem[BLOCK / 64];
    const int lane = threadIdx.x & 63;
    const int wave = threadIdx.x >> 6;
    if (lane == 0) smem[wave] = s;
    __syncthreads();

    if (threadIdx.x == 0)
        out[0] = smem[0] + smem[1] + smem[2] + smem[3];
}

extern "C" void kernel_launch(void* const* d_in, const int* in_sizes, int n_in,
                              void* d_out, int out_size, void* d_ws, size_t ws_size,
                              hipStream_t stream) {
    const float* pred = (const float*)d_in[0];
    const int* tgt = (const int*)d_in[1];
    float* out = (float*)d_out;
    float* partials = (float*)d_ws;  // NROWS floats, all written by pass 1

    const double eps_d = 0.1 / (double)(V - 2);
    const double C_d = (double)(V - 2) * eps_d * log(eps_d) + 0.9 * log(0.9);

    ls_row_kernel<<<NROWS, BLOCK, 0, stream>>>(pred, tgt, partials,
                                               (float)C_d, (float)eps_d);
    ls_final_kernel<<<1, BLOCK, 0, stream>>>(partials, out);
}